// Round 9
// baseline (149.790 us; speedup 1.0000x reference)
//
#include <hip/hip_runtime.h>

// VectorQuantizer: B=16,T=8192,D=64,K=1024
// out = [quantized 131072x64 f32][indices 131072 as f32]
// Round 9: 64 tokens/wave (LDS-read floor /2, prefetch slack x4), LDS-shared
// W chunks + g2l prefetch, in-register A-frag pipeline (named vars, no spill),
// r5-verified math: 3-term split-bf16, tracker, rescan @2e-3, coalesced epi.
#define MTOK  131072
#define DIMD  64
#define KCODE 1024
#define TPB   256        // tokens per block = 4 waves x 64 tokens

typedef __bf16 bf16x8 __attribute__((ext_vector_type(8)));
typedef float  f32x4  __attribute__((ext_vector_type(4)));

__device__ __forceinline__ f32x4 mfma16(bf16x8 a, bf16x8 b, f32x4 c) {
    return __builtin_amdgcn_mfma_f32_16x16x32_bf16(a, b, c, 0, 0, 0);
}

// async global->LDS, 16B/lane; LDS dest = wave-uniform base + lane*16
__device__ __forceinline__ void g2l16(const void* g, void* l) {
    __builtin_amdgcn_global_load_lds(
        (const __attribute__((address_space(1))) unsigned int*)g,
        (__attribute__((address_space(3))) unsigned int*)l, 16, 0, 0);
}

// ---- prep: pack W into MFMA-fragment order + e2 tables (r5-verified) ----
// wpk element offset = cb*2048 + win*512 + lane*8
// win: 0=hi d0-31, 1=hi d32-63, 2=lo d0-31, 3=lo d32-63
// lane=(q,m): frag = w[cb*16+m][(win&1)*32+q*8 ..+8]
__global__ __launch_bounds__(256) void prep_kernel(
    const float* __restrict__ w, __bf16* __restrict__ wpk,
    float* __restrict__ e2n, float* __restrict__ e2) {
    int b   = blockIdx.x;
    int tid = threadIdx.x;
    if (b < 64) {                       // pack blocks
        int cb  = b;
        int win = tid >> 6, lane = tid & 63;
        int q = lane >> 4, m = lane & 15;
        int k = cb * 16 + m;
        int d0 = (win & 1) * 32 + q * 8;
        const float* src = w + (size_t)k * DIMD + d0;
        float4 v0 = *(const float4*)(src);
        float4 v1 = *(const float4*)(src + 4);
        float f[8] = {v0.x, v0.y, v0.z, v0.w, v1.x, v1.y, v1.z, v1.w};
        bf16x8 o;
#pragma unroll
        for (int j = 0; j < 8; ++j) {
            __bf16 h = (__bf16)f[j];
            o[j] = (win < 2) ? h : (__bf16)(f[j] - (float)h);
        }
        *(bf16x8*)(wpk + ((size_t)(cb * 4 + win) * 64 + lane) * 8) = o;
    } else {                            // e2: one code/thread, exact r1 fma order
        int k2 = (b - 64) * 256 + tid;
        const float4* row = (const float4*)(w + (size_t)k2 * DIMD);
        float s = 0.f;
#pragma unroll
        for (int i = 0; i < 16; ++i) {
            float4 v = row[i];
            s = fmaf(v.x, v.x, s); s = fmaf(v.y, v.y, s);
            s = fmaf(v.z, v.z, s); s = fmaf(v.w, v.w, s);
        }
        e2[k2]  = s;
        e2n[k2] = -0.5f * s;
    }
}

__global__ __launch_bounds__(256, 2) void vq_main(
    const float* __restrict__ x, const float* __restrict__ wfull,
    const __bf16* __restrict__ wpk, const float* __restrict__ e2n_g,
    const float* __restrict__ e2_g, float* __restrict__ out) {

    // 2 x 16KB W chunk double-buffer + 4KB e2 = 36KB
    __shared__ __align__(16) __bf16 ldsW[2][8192];
    __shared__ __align__(16) float  ldsE[KCODE];

    const int tid  = threadIdx.x;
    const int blk  = blockIdx.x;
    const int lane = tid & 63;
    const int wv   = tid >> 6;      // wave -> tokens wv*64..+64
    const int q    = lane >> 4;
    const int m    = lane & 15;
    const size_t tok0 = (size_t)blk * TPB + wv * 64;   // wave's first token

    // ---- issue async stage: chunk 0 (16KB) + e2 table (4KB) ----
    {
        const char* gw = (const char*)wpk + (size_t)wv * 4096 + (size_t)lane * 16;
        char* lw = (char*)&ldsW[0][0] + wv * 4096 + lane * 16;
#pragma unroll
        for (int j = 0; j < 4; ++j)
            g2l16(gw + j * 1024, lw + j * 1024);
        g2l16((const char*)e2n_g + (size_t)wv * 1024 + lane * 16,
              (char*)ldsE + wv * 1024 + lane * 16);
    }

    // ---- x fragments straight from global, hi/lo split in registers ----
    bf16x8 bx[4][4];   // [token-group][win: xhi0,xhi1,xlo0,xlo1]
#pragma unroll
    for (int tg = 0; tg < 4; ++tg) {
        const float* xr = x + (tok0 + tg * 16 + m) * DIMD;
#pragma unroll
        for (int h = 0; h < 2; ++h) {
            float4 v0 = *(const float4*)(xr + h * 32 + q * 8);
            float4 v1 = *(const float4*)(xr + h * 32 + q * 8 + 4);
            float f[8] = {v0.x, v0.y, v0.z, v0.w, v1.x, v1.y, v1.z, v1.w};
            bf16x8 hi, lo;
#pragma unroll
            for (int j = 0; j < 8; ++j) {
                __bf16 hh = (__bf16)f[j];
                hi[j] = hh;
                lo[j] = (__bf16)(f[j] - (float)hh);
            }
            bx[tg][h]     = hi;
            bx[tg][2 + h] = lo;
        }
    }

    float b1[4], b2[4]; int i1[4];
#pragma unroll
    for (int tg = 0; tg < 4; ++tg) { b1[tg] = -3e38f; b2[tg] = -3e38f; i1[tg] = 0; }

    // acc = dot - e2/2 (C-init); argmax(acc) == argmin(dist). Tracker: top-1
    // (value+idx, strict > => ties keep lower code) + top-2 value (med3).
    auto step = [&](bf16x8 f0, bf16x8 f1, bf16x8 f2, bf16x8 f3, f32x4 ee, int cbase) {
#pragma unroll
        for (int tg = 0; tg < 4; ++tg) {
            f32x4 t = mfma16(f0, bx[tg][0], ee);   // w_hi*x_hi d0-31
            t = mfma16(f1, bx[tg][1], t);          // w_hi*x_hi d32-63
            t = mfma16(f0, bx[tg][2], t);          // w_hi*x_lo
            t = mfma16(f1, bx[tg][3], t);
            t = mfma16(f2, bx[tg][0], t);          // w_lo*x_hi
            t = mfma16(f3, bx[tg][1], t);
#pragma unroll
            for (int r = 0; r < 4; ++r) {
                float a   = t[r];
                int idxv  = cbase + q * 4 + r;
                bool gt   = a > b1[tg];
                i1[tg] = gt ? idxv : i1[tg];
                b2[tg] = __builtin_amdgcn_fmed3f(a, b1[tg], b2[tg]);
                b1[tg] = fmaxf(a, b1[tg]);
            }
        }
    };

    __syncthreads();   // chunk 0 + e2 resident (barrier drains vmcnt)

    // ---- main loop: 16 chunks x 64 codes; g2l prefetch next chunk under
    //      compute; in-register A-frag pipeline within the chunk ----
    for (int c = 0; c < 16; ++c) {
        if (c + 1 < 16) {
            const char* gw = (const char*)wpk + (size_t)(c + 1) * 16384
                           + (size_t)wv * 4096 + (size_t)lane * 16;
            char* lw = (char*)&ldsW[(c + 1) & 1][0] + wv * 4096 + lane * 16;
#pragma unroll
            for (int j = 0; j < 4; ++j)
                g2l16(gw + j * 1024, lw + j * 1024);
        }
        const __bf16* wb = &ldsW[c & 1][0] + lane * 8;   // frag base; rest imm
        // prime cb=0 fragments
        bf16x8 a0 = *(const bf16x8*)(wb + 0);
        bf16x8 a1 = *(const bf16x8*)(wb + 512);
        bf16x8 a2 = *(const bf16x8*)(wb + 1024);
        bf16x8 a3 = *(const bf16x8*)(wb + 1536);
#pragma unroll
        for (int cbl = 0; cbl < 4; ++cbl) {
            bf16x8 c0 = a0, c1 = a1, c2 = a2, c3 = a3;
            if (cbl + 1 < 4) {           // read next cb's frags before stepping
                a0 = *(const bf16x8*)(wb + (cbl + 1) * 2048 + 0);
                a1 = *(const bf16x8*)(wb + (cbl + 1) * 2048 + 512);
                a2 = *(const bf16x8*)(wb + (cbl + 1) * 2048 + 1024);
                a3 = *(const bf16x8*)(wb + (cbl + 1) * 2048 + 1536);
            }
            f32x4 ee = *(const f32x4*)&ldsE[c * 64 + cbl * 16 + q * 4];
            step(c0, c1, c2, c3, ee, (c * 4 + cbl) * 16);
        }
        __syncthreads();   // all waves done with buf c&1; prefetch c+1 landed
    }

    // ---- cross-quad merge: lanes m,m+16,m+32,m+48 hold disjoint code sets ----
    float B1f[4], B2f[4]; int I1f[4];
#pragma unroll
    for (int tg = 0; tg < 4; ++tg) {
        float B1 = b1[tg], B2 = b2[tg]; int I1 = i1[tg];
#pragma unroll
        for (int mask = 16; mask <= 32; mask <<= 1) {
            float ob1 = __shfl_xor(B1, mask);
            float ob2 = __shfl_xor(B2, mask);
            int   oi  = __shfl_xor(I1, mask);
            bool take = (ob1 > B1) || (ob1 == B1 && oi < I1);
            B2 = fmaxf(fminf(ob1, B1), fmaxf(ob2, B2));
            I1 = take ? oi : I1;
            B1 = fmaxf(ob1, B1);
        }
        B1f[tg] = B1; B2f[tg] = B2; I1f[tg] = I1;   // replicated across quads
    }

    // token t (0..63) of this wave -> its index; lane L owns token L
    int myidx;
    {
        int src = lane & 15;
        int v0 = __shfl(I1f[0], src);
        int v1 = __shfl(I1f[1], src);
        int v2 = __shfl(I1f[2], src);
        int v3 = __shfl(I1f[3], src);
        int sel = lane >> 4;
        myidx = (sel == 0) ? v0 : (sel == 1) ? v1 : (sel == 2) ? v2 : v3;
    }

    // ---- ballot-driven exact fp32 rescan of near-ties (round-1 numerics) ----
#pragma unroll
    for (int tg = 0; tg < 4; ++tg) {
        unsigned long long msk =
            __ballot((lane < 16) && (B1f[tg] - B2f[tg] < 2e-3f));
        while (msk) {
            int mm = __ffsll((unsigned long long)msk) - 1;
            msk &= msk - 1;
            int tloc = tg * 16 + mm;              // token within this wave (0..63)
            const float4* xr = (const float4*)(x + (tok0 + tloc) * DIMD);
            float bv = 3e38f; int bi = 0;
            for (int j = 0; j < 16; ++j) {
                int k = lane * 16 + j;
                const float4* wr = (const float4*)(wfull + (size_t)k * DIMD);
                float s = 0.f;
#pragma unroll
                for (int i = 0; i < 16; ++i) {
                    float4 xv = xr[i], wv4 = wr[i];
                    s = fmaf(xv.x, wv4.x, s); s = fmaf(xv.y, wv4.y, s);
                    s = fmaf(xv.z, wv4.z, s); s = fmaf(xv.w, wv4.w, s);
                }
                float dv = fmaf(-2.f, s, e2_g[k]);
                if (dv < bv) { bv = dv; bi = k; }  // ties -> lower k
            }
#pragma unroll
            for (int mask2 = 1; mask2 <= 32; mask2 <<= 1) {
                float ov = __shfl_xor(bv, mask2);
                int   oi = __shfl_xor(bi, mask2);
                bool take = (ov < bv) || (ov == bv && oi < bi);
                bv = take ? ov : bv;
                bi = take ? oi : bi;
            }
            myidx = (lane == tloc) ? bi : myidx;
        }
    }

    // ---- outputs ----
    // indices as f32 (lane L owns token L of this wave)
    out[(size_t)MTOK * DIMD + tok0 + lane] = (float)myidx;

    // coalesced gather: per j, wave writes one contiguous 1KB segment;
    // codebook row read cooperatively (16 lanes per row, contiguous 256B)
    {
        float* obase = out + tok0 * DIMD;
#pragma unroll
        for (int j = 0; j < 16; ++j) {
            int srcl = j * 4 + (lane >> 4);        // token 0..63
            int gi   = __shfl(myidx, srcl);
            float4 v = *(const float4*)(wfull + (size_t)gi * DIMD + (lane & 15) * 4);
            *(float4*)(obase + j * 256 + lane * 4) = v;
        }
    }
}

extern "C" void kernel_launch(void* const* d_in, const int* in_sizes, int n_in,
                              void* d_out, int out_size, void* d_ws, size_t ws_size,
                              hipStream_t stream) {
    const float* x = (const float*)d_in[0];
    const float* w = (const float*)d_in[1];
    float* out = (float*)d_out;

    // ws: [wpk 256K][e2n 4K][e2 4K]
    __bf16* wpk = (__bf16*)d_ws;
    float*  e2n = (float*)((char*)d_ws + 262144);
    float*  e2  = (float*)((char*)d_ws + 266240);

    prep_kernel<<<68, 256, 0, stream>>>(w, wpk, e2n, e2);
    vq_main<<<MTOK / TPB, 256, 0, stream>>>(x, w, wpk, e2n, e2, out);
}